// Round 2
// baseline (685.809 us; speedup 1.0000x reference)
//
#include <hip/hip_runtime.h>
#include <hip/hip_bf16.h>

#define LNUM 6
#define BATCH 131072

typedef __bf16 bf16x8 __attribute__((ext_vector_type(8)));
typedef float f32x16 __attribute__((ext_vector_type(16)));
typedef float f32x4  __attribute__((ext_vector_type(4)));

// ---------------- ws layout ----------------
// 36 W blocks, each 256x256 bf16 = 131072 B:
// [nh(2)][kk(16)][nti(4)][lane(64)][16B]
//   n = (nh*4+nti)*32 + (l&31), k = kk*16 + (l>>5)*8 + jj
#define WFRAG_BYTES 131072ul
#define W1B1_OFF 4718592ul   // 12 x (256 f32 W1row || 256 f32 B1)
#define BIAS_OFF 4743168ul   // 36 x 256 f32 (B2/B3/B4)
#define W5_OFF   4780032ul   // 12 x 272 f32 (W5 column || B5 || pad)
#define WS_NEEDED 4793088ul

struct PtrPack { const float* p[21]; };

// -------- prep: pack W2/W3/W4 into MFMA fragment order (verified r4-r17) --------
__global__ void prep_w(PtrPack P, unsigned char* __restrict__ ws) {
    int t = blockIdx.x * 256 + threadIdx.x;
    int blk = t >> 13;
    int e8  = t & 8191;
    int nh  = e8 >> 12;
    int kk  = (e8 >> 8) & 15;
    int nti = (e8 >> 6) & 3;
    int l   = e8 & 63;
    int nt = nh * 4 + nti;
    int n  = nt * 32 + (l & 31);
    int k0 = kk * 16 + (l >> 5) * 8;
    int net = blk / 18, rem = blk % 18;
    int i = rem / 3, g = rem % 3;
    const float* src = P.p[3 + g * 2 + net * 10] + i * 65536;
    bf16x8 v;
#pragma unroll
    for (int jj = 0; jj < 8; ++jj) v[jj] = (__bf16)src[(k0 + jj) * 256 + n];
    *(bf16x8*)(ws + (unsigned long)blk * WFRAG_BYTES + (unsigned)e8 * 16) = v;
}

// -------- prep: W1 row / B1, biases, W5 column / B5 (f32, verified) --------
__global__ void prep_small(PtrPack P, unsigned char* __restrict__ ws) {
    int t = blockIdx.x * 256 + threadIdx.x;
    if (t < 6144) {
        int idx = t >> 9, e = t & 511;
        int net = idx / 6, i = idx % 6;
        int j = (i & 1) ? 0 : 1;
        float v;
        if (e < 256) v = P.p[1 + net * 10][i * 512 + j * 256 + e];
        else         v = P.p[2 + net * 10][i * 256 + (e - 256)];
        ((float*)(ws + W1B1_OFF))[t] = v;
    } else if (t < 6144 + 9216) {
        int u = t - 6144;
        int idx = u >> 8, e = u & 255;
        int net = idx / 18, rem = idx % 18, i = rem / 3, g = rem % 3;
        ((float*)(ws + BIAS_OFF))[u] = P.p[4 + g * 2 + net * 10][i * 256 + e];
    } else if (t < 6144 + 9216 + 12 * 272) {
        int u = t - 6144 - 9216;
        int idx = u / 272, e = u % 272;
        int net = idx / 6, i = idx % 6;
        int ud = (i & 1) ? 1 : 0;
        float v = 0.f;
        if (e < 256)      v = P.p[9 + net * 10][i * 512 + e * 2 + ud];
        else if (e == 256) v = P.p[10 + net * 10][i * 2 + ud];
        ((float*)(ws + W5_OFF))[idx * 272 + e] = v;
    }
}

// ---------------- main fused kernel ----------------
// r19 structure: 512-thread block (8 waves), ONE shared 128-row A-tile,
// each wave owns a 32-col n-slice -> acc = 4 x f32x16 (64 regs, was 128).
// __launch_bounds__(512,4) caps VGPR at 128 -> 2 blocks/CU = 4 waves/SIMD
// (double r16's occupancy). Rationale: r18's forced k-loop alternation did
// NOT raise MfmaUtil -> idle pipe is an occupancy problem (serial phases
// fully exposed at 2 waves/SIMD), not a phase-lock problem. Rows stay 128
// so per-CU weight traffic is unchanged (r13/r15/r17 losses were row-tile
// losses). Per-wave serial VALU halves; wq-ring cover doubles in wall
// cycles at 4-wave cadence. Plain __syncthreads throughout.
#define L_A   0
#define L_Z0  65536
#define L_Z1  66048
#define L_LD  66560
#define L_RED 67072   // [8 waves][128 rows] f32
#define L_OS  71168   // oS[128]
#define L_TOT 71680

__device__ __forceinline__ unsigned pk2(float a, float b) {
    unsigned short ua = __builtin_bit_cast(unsigned short, (__bf16)a);
    unsigned short ub = __builtin_bit_cast(unsigned short, (__bf16)b);
    return (unsigned)ua | ((unsigned)ub << 16);
}

__global__ __launch_bounds__(512, 4) void realnvp_main(
        const float* __restrict__ x, const unsigned char* __restrict__ ws,
        float* __restrict__ out) {
    __shared__ __align__(16) unsigned char lds[L_TOT];
    const int tid = threadIdx.x;
    const int wv = tid >> 6, lane = tid & 63;
    const int li = lane & 31, hi = lane >> 5;
    float* zA  = (float*)(lds + L_Z0);
    float* zB  = (float*)(lds + L_Z1);
    float* ldt = (float*)(lds + L_LD);
    float* red = (float*)(lds + L_RED);
    float* oSa = (float*)(lds + L_OS);
    const float* w1b1_g = (const float*)(ws + W1B1_OFF);
    const float* bias_g = (const float*)(ws + BIAS_OFF);
    const float* w5_g   = (const float*)(ws + W5_OFF);

    // LDS row addressing: byte(row,kB) = row*512 + (kB ^ ((row&7)<<4));
    // every row this lane touches has row&7 == lane&7 -> one swizzle constant
    const unsigned swr = (unsigned)((lane & 7) << 4);

    if (tid < 128) {
        float2 xv = ((const float2*)x)[blockIdx.x * 128 + tid];
        zA[tid] = logf(xv.x) - logf(1.f - xv.x);
        zB[tid] = logf(xv.y) - logf(1.f - xv.y);
        ldt[tid] = 0.f;
    }
    __syncthreads();

    // layer-1 work split: 4 threads per row (kq = k-quarter), 16 rows per wave
    const int li4 = lane & 15, kq = lane >> 4;
    const int r1row = wv * 16 + li4;

#pragma unroll 1
    for (int ii = 0; ii < LNUM; ++ii) {
        const int i = 5 - ii;
#pragma unroll 1
        for (int net = 0; net < 2; ++net) {
            // ---- layer 1: A[row][k] = relu(z*W1[k]+B1[k]); b128 stores ----
            {
                const float* w1 = w1b1_g + (net * 6 + i) * 512;
                const float zj = ((i & 1) ? zA : zB)[r1row];
                unsigned char* rowp = lds + L_A + r1row * 512;
#pragma unroll 4
                for (int jj = 0; jj < 8; ++jj) {
                    const int k0 = kq * 64 + jj * 8;
                    f32x4 w0 = *(const f32x4*)(w1 + k0);
                    f32x4 w1v = *(const f32x4*)(w1 + k0 + 4);
                    f32x4 b0 = *(const f32x4*)(w1 + 256 + k0);
                    f32x4 b1v = *(const f32x4*)(w1 + 256 + k0 + 4);
                    uint4 v;
                    v.x = pk2(fmaxf(zj * w0[0] + b0[0], 0.f), fmaxf(zj * w0[1] + b0[1], 0.f));
                    v.y = pk2(fmaxf(zj * w0[2] + b0[2], 0.f), fmaxf(zj * w0[3] + b0[3], 0.f));
                    v.z = pk2(fmaxf(zj * w1v[0] + b1v[0], 0.f), fmaxf(zj * w1v[1] + b1v[1], 0.f));
                    v.w = pk2(fmaxf(zj * w1v[2] + b1v[2], 0.f), fmaxf(zj * w1v[3] + b1v[3], 0.f));
                    *(uint4*)(rowp + (((unsigned)(k0 * 2)) ^ swr)) = v;
                }
            }
            __syncthreads();
#pragma unroll 1
            for (int g = 0; g < 3; ++g) {
                const int blk = (net * 6 + i) * 3 + g;
                // wave wv owns n-tile wv: nh = wv>>2 (stride 64KB), nti = wv&3 (stride 1KB)
                const unsigned char* wbase = ws + (unsigned long)blk * WFRAG_BYTES
                        + (unsigned)(wv >> 2) * 65536 + (unsigned)(wv & 3) * 1024
                        + (unsigned)lane * 16;
                const float* biasl = bias_g + blk * 256 + wv * 32;
                const float* w5 = w5_g + (net * 6 + i) * 272;

                f32x16 acc[4];   // [rt]: rows rt*32.., n = wv*32 + c + 8q + 4hi
#pragma unroll
                for (int q = 0; q < 4; ++q) {
                    f32x4 bb = *(const f32x4*)(biasl + q * 8 + hi * 4);
#pragma unroll
                    for (int rt = 0; rt < 4; ++rt) {
                        acc[rt][4 * q + 0] = bb[0];
                        acc[rt][4 * q + 1] = bb[1];
                        acc[rt][4 * q + 2] = bb[2];
                        acc[rt][4 * q + 3] = bb[3];
                    }
                }
                // weight ring (global->reg, 3 k-steps deep) + act ping-pong
                bf16x8 wq[3];
#pragma unroll
                for (int p = 0; p < 3; ++p)
                    wq[p] = *(const bf16x8*)(wbase + p * 4096);
                bf16x8 aa[2][4];
#pragma unroll
                for (int rt = 0; rt < 4; ++rt)
                    aa[0][rt] = *(const bf16x8*)(lds + L_A + (rt * 32 + li) * 512
                                                 + (((unsigned)(hi * 16)) ^ swr));
#pragma unroll
                for (int k = 0; k < 16; ++k) {
                    const int cur = k & 1, nxt = cur ^ 1;
                    if (k < 15) {
#pragma unroll
                        for (int rt = 0; rt < 4; ++rt)
                            aa[nxt][rt] = *(const bf16x8*)(lds + L_A + (rt * 32 + li) * 512
                                          + (((unsigned)((k + 1) * 32 + hi * 16)) ^ swr));
                    }
                    __builtin_amdgcn_s_setprio(1);
#pragma unroll
                    for (int rt = 0; rt < 4; ++rt)
                        acc[rt] = __builtin_amdgcn_mfma_f32_32x32x16_bf16(wq[k % 3], aa[cur][rt], acc[rt], 0, 0, 0);
                    __builtin_amdgcn_s_setprio(0);
                    if (k < 13)
                        wq[k % 3] = *(const bf16x8*)(wbase + (k + 3) * 4096);
                }
                __syncthreads();   // all waves done reading A
                if (g < 2) {
                    // epilogue: relu -> bf16 pairs -> in-place A[row][n] writes
#pragma unroll
                    for (int rt = 0; rt < 4; ++rt) {
                        unsigned char* rp = lds + L_A + (rt * 32 + li) * 512;
#pragma unroll
                        for (int q = 0; q < 4; ++q) {
                            const f32x16& A = acc[rt];
                            unsigned lo = pk2(fmaxf(A[4 * q + 0], 0.f), fmaxf(A[4 * q + 1], 0.f));
                            unsigned h2 = pk2(fmaxf(A[4 * q + 2], 0.f), fmaxf(A[4 * q + 3], 0.f));
                            const unsigned nB = (unsigned)((wv * 32 + q * 8 + hi * 4) * 2);
                            *(uint2*)(rp + (nB ^ swr)) = make_uint2(lo, h2);
                        }
                    }
                    __syncthreads();
                } else {
                    // layer-5 dot over this wave's 32-col slice, then cross-wave reduce
                    float part[4] = {0.f, 0.f, 0.f, 0.f};
#pragma unroll
                    for (int q = 0; q < 4; ++q) {
                        f32x4 ww = *(const f32x4*)(w5 + wv * 32 + q * 8 + hi * 4);
#pragma unroll
                        for (int rt = 0; rt < 4; ++rt)
#pragma unroll
                            for (int c = 0; c < 4; ++c)
                                part[rt] += fmaxf(acc[rt][4 * q + c], 0.f) * ww[c];
                    }
#pragma unroll
                    for (int rt = 0; rt < 4; ++rt) part[rt] += __shfl_xor(part[rt], 32);
                    if (hi == 0) {
#pragma unroll
                        for (int rt = 0; rt < 4; ++rt) red[wv * 128 + rt * 32 + li] = part[rt];
                    }
                    __syncthreads();
                    if (tid < 128) {
                        float o = w5[256];
#pragma unroll
                        for (int w8 = 0; w8 < 8; ++w8) o += red[w8 * 128 + tid];
                        if (net == 0) {
                            oSa[tid] = o;
                        } else {
                            const float s = tanhf(oSa[tid]);
                            const float e = expf(-s);
                            if (i & 1) zB[tid] = (zB[tid] - o) * e;
                            else       zA[tid] = (zA[tid] - o) * e;
                            ldt[tid] -= s;
                        }
                    }
                    __syncthreads();
                }
            }
        }
    }
    if (tid < 128) {
        const int row = blockIdx.x * 128 + tid;
        ((float2*)out)[row] = make_float2(1.f / (1.f + expf(-zA[tid])),
                                          1.f / (1.f + expf(-zB[tid])));
        out[2 * BATCH + row] = ldt[tid];
    }
}

extern "C" void kernel_launch(void* const* d_in, const int* in_sizes, int n_in,
                              void* d_out, int out_size, void* d_ws, size_t ws_size,
                              hipStream_t stream) {
    if (ws_size < WS_NEEDED) return;
    PtrPack P;
    for (int k = 0; k < 21; ++k) P.p[k] = (const float*)d_in[k];
    unsigned char* ws = (unsigned char*)d_ws;
    prep_w<<<dim3(1152), dim3(256), 0, stream>>>(P, ws);
    prep_small<<<dim3(73), dim3(256), 0, stream>>>(P, ws);
    realnvp_main<<<dim3(1024), dim3(512), 0, stream>>>((const float*)d_in[0], ws, (float*)d_out);
}

// Round 3
// 522.903 us; speedup vs baseline: 1.3115x; 1.3115x over previous
//
#include <hip/hip_runtime.h>
#include <hip/hip_bf16.h>

#define LNUM 6
#define BATCH 131072

typedef __bf16 bf16x8 __attribute__((ext_vector_type(8)));
typedef float f32x16 __attribute__((ext_vector_type(16)));
typedef float f32x4  __attribute__((ext_vector_type(4)));

// ---------------- ws layout ----------------
// 36 W blocks, each 256x256 bf16 = 131072 B:
// [nh(2)][kk(16)][nti(4)][lane(64)][16B]
//   n = (nh*4+nti)*32 + (l&31), k = kk*16 + (l>>5)*8 + jj
#define WFRAG_BYTES 131072ul
#define W1B1_OFF 4718592ul   // 12 x (256 f32 W1row || 256 f32 B1)
#define BIAS_OFF 4743168ul   // 36 x 256 f32 (B2/B3/B4)
#define W5_OFF   4780032ul   // 12 x 272 f32 (W5 column || B5 || pad)
#define WS_NEEDED 4793088ul

struct PtrPack { const float* p[21]; };

// -------- prep: pack W2/W3/W4 into MFMA fragment order (verified r4-r17) --------
__global__ void prep_w(PtrPack P, unsigned char* __restrict__ ws) {
    int t = blockIdx.x * 256 + threadIdx.x;
    int blk = t >> 13;
    int e8  = t & 8191;
    int nh  = e8 >> 12;
    int kk  = (e8 >> 8) & 15;
    int nti = (e8 >> 6) & 3;
    int l   = e8 & 63;
    int nt = nh * 4 + nti;
    int n  = nt * 32 + (l & 31);
    int k0 = kk * 16 + (l >> 5) * 8;
    int net = blk / 18, rem = blk % 18;
    int i = rem / 3, g = rem % 3;
    const float* src = P.p[3 + g * 2 + net * 10] + i * 65536;
    bf16x8 v;
#pragma unroll
    for (int jj = 0; jj < 8; ++jj) v[jj] = (__bf16)src[(k0 + jj) * 256 + n];
    *(bf16x8*)(ws + (unsigned long)blk * WFRAG_BYTES + (unsigned)e8 * 16) = v;
}

// -------- prep: W1 row / B1, biases, W5 column / B5 (f32, verified) --------
__global__ void prep_small(PtrPack P, unsigned char* __restrict__ ws) {
    int t = blockIdx.x * 256 + threadIdx.x;
    if (t < 6144) {
        int idx = t >> 9, e = t & 511;
        int net = idx / 6, i = idx % 6;
        int j = (i & 1) ? 0 : 1;
        float v;
        if (e < 256) v = P.p[1 + net * 10][i * 512 + j * 256 + e];
        else         v = P.p[2 + net * 10][i * 256 + (e - 256)];
        ((float*)(ws + W1B1_OFF))[t] = v;
    } else if (t < 6144 + 9216) {
        int u = t - 6144;
        int idx = u >> 8, e = u & 255;
        int net = idx / 18, rem = idx % 18, i = rem / 3, g = rem % 3;
        ((float*)(ws + BIAS_OFF))[u] = P.p[4 + g * 2 + net * 10][i * 256 + e];
    } else if (t < 6144 + 9216 + 12 * 272) {
        int u = t - 6144 - 9216;
        int idx = u / 272, e = u % 272;
        int net = idx / 6, i = idx % 6;
        int ud = (i & 1) ? 1 : 0;
        float v = 0.f;
        if (e < 256)      v = P.p[9 + net * 10][i * 512 + e * 2 + ud];
        else if (e == 256) v = P.p[10 + net * 10][i * 2 + ud];
        ((float*)(ws + W5_OFF))[idx * 272 + e] = v;
    }
}

// ---------------- main fused kernel ----------------
// r21: back to the proven r16 shape (256 thr, 4 waves, 128 rows x 64-col
// slices, acc 128 AGPR, 2 blocks/CU) but A stored in MFMA FRAGMENT ORDER
// A[kk(16)][rt(4)][lane(64)][16B]:
//  - k-loop aa reads: base + lane*16 + imm(kk*4096+rt*1024) -> contiguous
//    1KB per ds_read_b128, conflict-free, zero address VALU (was 4-way
//    conflicted through the XOR swizzle: SQ_LDS_BANK_CONFLICT 5e7).
//  - epilogue: acc (row=rt*32+li, n=wv*64+j2*32+q*8+hi*4+c) -> frag addr
//    kk=wv*4+j2*2+(q>>1), lane=(q&1)*32+li, byte=hi*8: 512B-contiguous
//    uint2 stores, conflict-free.
//  - layer 1 becomes a 1-k-step MFMA: A-operand built in-register from z
//    (z=zh+zl split; W1=Wh+Wl split; bias via k*1.0 slots -> error ~2^-17),
//    W-operand built from the f32 W1B1 table. Replaces 480 VALU + 64
//    global loads per thread per pass; epilogue shared with the GEMMs.
// Registers/occupancy/barriers unchanged vs the 549us baseline.
#define L_A   0       // 16*4096 = 65536
#define L_Z0  65536
#define L_Z1  66048
#define L_LD  66560
#define L_RED 67072   // [4 waves][128 rows] f32
#define L_OS  69120   // oS[128]
#define L_TOT 69632

__device__ __forceinline__ unsigned pk2(float a, float b) {
    unsigned short ua = __builtin_bit_cast(unsigned short, (__bf16)a);
    unsigned short ub = __builtin_bit_cast(unsigned short, (__bf16)b);
    return (unsigned)ua | ((unsigned)ub << 16);
}

__global__ __launch_bounds__(256, 2) void realnvp_main(
        const float* __restrict__ x, const unsigned char* __restrict__ ws,
        float* __restrict__ out) {
    __shared__ __align__(16) unsigned char lds[L_TOT];
    const int tid = threadIdx.x;
    const int wv = tid >> 6, lane = tid & 63;
    const int li = lane & 31, hi = lane >> 5;
    float* zA  = (float*)(lds + L_Z0);
    float* zB  = (float*)(lds + L_Z1);
    float* ldt = (float*)(lds + L_LD);
    float* red = (float*)(lds + L_RED);
    float* oSa = (float*)(lds + L_OS);
    const float* w1b1_g = (const float*)(ws + W1B1_OFF);
    const float* bias_g = (const float*)(ws + BIAS_OFF);
    const float* w5_g   = (const float*)(ws + W5_OFF);

    // frag-layout bases (all k-loop/epilogue offsets are compile-time imms)
    const unsigned char* aaBase = lds + L_A + (unsigned)lane * 16;
    unsigned char* const stBase = lds + L_A + (unsigned)(li * 16 + hi * 8);

    if (tid < 128) {
        float2 xv = ((const float2*)x)[blockIdx.x * 128 + tid];
        zA[tid] = logf(xv.x) - logf(1.f - xv.x);
        zB[tid] = logf(xv.y) - logf(1.f - xv.y);
        ldt[tid] = 0.f;
    }
    __syncthreads();

    // shared epilogue: relu -> bf16 pairs -> A-frag stores (conflict-free)
    auto storeA = [&](const f32x16* a) {
#pragma unroll
        for (int rt = 0; rt < 4; ++rt)
#pragma unroll
            for (int j2 = 0; j2 < 2; ++j2)
#pragma unroll
                for (int q = 0; q < 4; ++q) {
                    const f32x16& A = a[rt * 2 + j2];
                    unsigned lo = pk2(fmaxf(A[4 * q + 0], 0.f), fmaxf(A[4 * q + 1], 0.f));
                    unsigned h2 = pk2(fmaxf(A[4 * q + 2], 0.f), fmaxf(A[4 * q + 3], 0.f));
                    const unsigned off = (unsigned)((wv * 4 + j2 * 2 + (q >> 1)) * 4096
                                                    + rt * 1024 + (q & 1) * 512);
                    *(uint2*)(stBase + off) = make_uint2(lo, h2);
                }
    };

#pragma unroll 1
    for (int ii = 0; ii < LNUM; ++ii) {
        const int i = 5 - ii;
#pragma unroll 1
        for (int net = 0; net < 2; ++net) {
            // ---- layer 1 as a single-k-step MFMA ----
            {
                const float* w1 = w1b1_g + (net * 6 + i) * 512;
                const float* zArr = (i & 1) ? zA : zB;
                bf16x8 wf[2], af[4];
                const bf16x8 zr = {};
                if (hi == 0) {
#pragma unroll
                    for (int f = 0; f < 2; ++f) {
                        const int n = (wv * 2 + f) * 32 + li;
                        const float W = w1[n], B = w1[256 + n];
                        const __bf16 Wh = (__bf16)W;
                        const __bf16 Wl = (__bf16)(W - (float)Wh);
                        const __bf16 Bh = (__bf16)B;
                        const __bf16 Bl = (__bf16)(B - (float)Bh);
                        bf16x8 t = zr;
                        t[0] = Wh; t[1] = Wl; t[2] = Wh; t[3] = Bh; t[4] = Bl;
                        wf[f] = t;
                    }
#pragma unroll
                    for (int rt = 0; rt < 4; ++rt) {
                        const float z = zArr[rt * 32 + li];
                        const __bf16 zh = (__bf16)z;
                        const __bf16 zl = (__bf16)(z - (float)zh);
                        bf16x8 t = zr;
                        t[0] = zh; t[1] = zh; t[2] = zl;
                        t[3] = (__bf16)1.f; t[4] = (__bf16)1.f;
                        af[rt] = t;
                    }
                } else {
                    wf[0] = zr; wf[1] = zr;
                    af[0] = zr; af[1] = zr; af[2] = zr; af[3] = zr;
                }
                f32x16 acc1[8];
#pragma unroll
                for (int u = 0; u < 8; ++u)
#pragma unroll
                    for (int e = 0; e < 16; ++e) acc1[u][e] = 0.f;
#pragma unroll
                for (int rt = 0; rt < 4; ++rt) {
                    acc1[rt * 2 + 0] = __builtin_amdgcn_mfma_f32_32x32x16_bf16(wf[0], af[rt], acc1[rt * 2 + 0], 0, 0, 0);
                    acc1[rt * 2 + 1] = __builtin_amdgcn_mfma_f32_32x32x16_bf16(wf[1], af[rt], acc1[rt * 2 + 1], 0, 0, 0);
                }
                storeA(acc1);
            }
            __syncthreads();
#pragma unroll 1
            for (int g = 0; g < 3; ++g) {
                const int blk = (net * 6 + i) * 3 + g;
                const unsigned char* wbase = ws + (unsigned long)blk * WFRAG_BYTES
                        + (unsigned)(wv >> 1) * 65536 + (unsigned)(wv & 1) * 2048
                        + (unsigned)lane * 16;
                const float* biasl = bias_g + blk * 256 + wv * 64;
                const float* w5 = w5_g + (net * 6 + i) * 272;

                f32x16 acc[8];   // [rt*2 + j]: rows rt*32.., n = wv*64 + j*32 ..
#pragma unroll
                for (int j2 = 0; j2 < 2; ++j2)
#pragma unroll
                    for (int q = 0; q < 4; ++q) {
                        f32x4 bb = *(const f32x4*)(biasl + j2 * 32 + q * 8 + hi * 4);
#pragma unroll
                        for (int rt = 0; rt < 4; ++rt) {
                            acc[rt * 2 + j2][4 * q + 0] = bb[0];
                            acc[rt * 2 + j2][4 * q + 1] = bb[1];
                            acc[rt * 2 + j2][4 * q + 2] = bb[2];
                            acc[rt * 2 + j2][4 * q + 3] = bb[3];
                        }
                    }
                // weight ring (global->reg, 3 k-steps deep) + act ping-pong
                bf16x8 wq[3][2];
#pragma unroll
                for (int p = 0; p < 3; ++p) {
                    wq[p][0] = *(const bf16x8*)(wbase + p * 4096);
                    wq[p][1] = *(const bf16x8*)(wbase + p * 4096 + 1024);
                }
                bf16x8 aa[2][4];
#pragma unroll
                for (int rt = 0; rt < 4; ++rt)
                    aa[0][rt] = *(const bf16x8*)(aaBase + rt * 1024);
#pragma unroll
                for (int k = 0; k < 16; ++k) {
                    const int cur = k & 1, nxt = cur ^ 1;
                    if (k < 15) {
#pragma unroll
                        for (int rt = 0; rt < 4; ++rt)
                            aa[nxt][rt] = *(const bf16x8*)(aaBase + (k + 1) * 4096 + rt * 1024);
                    }
                    __builtin_amdgcn_s_setprio(1);
#pragma unroll
                    for (int rt = 0; rt < 4; ++rt) {
                        acc[rt * 2 + 0] = __builtin_amdgcn_mfma_f32_32x32x16_bf16(wq[k % 3][0], aa[cur][rt], acc[rt * 2 + 0], 0, 0, 0);
                        acc[rt * 2 + 1] = __builtin_amdgcn_mfma_f32_32x32x16_bf16(wq[k % 3][1], aa[cur][rt], acc[rt * 2 + 1], 0, 0, 0);
                    }
                    __builtin_amdgcn_s_setprio(0);
                    if (k < 13) {
                        wq[k % 3][0] = *(const bf16x8*)(wbase + (k + 3) * 4096);
                        wq[k % 3][1] = *(const bf16x8*)(wbase + (k + 3) * 4096 + 1024);
                    }
                }
                __syncthreads();   // all waves done reading A
                if (g < 2) {
                    storeA(acc);
                    __syncthreads();
                } else {
                    // layer-5 dot over this wave's n-slice, then cross-wave reduce
                    float part[4] = {0.f, 0.f, 0.f, 0.f};
#pragma unroll
                    for (int j2 = 0; j2 < 2; ++j2)
#pragma unroll
                        for (int q = 0; q < 4; ++q) {
                            f32x4 ww = *(const f32x4*)(w5 + wv * 64 + j2 * 32 + q * 8 + hi * 4);
#pragma unroll
                            for (int rt = 0; rt < 4; ++rt)
#pragma unroll
                                for (int c = 0; c < 4; ++c)
                                    part[rt] += fmaxf(acc[rt * 2 + j2][4 * q + c], 0.f) * ww[c];
                        }
#pragma unroll
                    for (int rt = 0; rt < 4; ++rt) part[rt] += __shfl_xor(part[rt], 32);
                    if (hi == 0) {
#pragma unroll
                        for (int rt = 0; rt < 4; ++rt) red[wv * 128 + rt * 32 + li] = part[rt];
                    }
                    __syncthreads();
                    if (tid < 128) {
                        const float o = red[tid] + red[128 + tid] + red[256 + tid] + red[384 + tid]
                                        + w5[256];
                        if (net == 0) {
                            oSa[tid] = o;
                        } else {
                            const float s = tanhf(oSa[tid]);
                            const float e = expf(-s);
                            if (i & 1) zB[tid] = (zB[tid] - o) * e;
                            else       zA[tid] = (zA[tid] - o) * e;
                            ldt[tid] -= s;
                        }
                    }
                    __syncthreads();
                }
            }
        }
    }
    if (tid < 128) {
        const int row = blockIdx.x * 128 + tid;
        ((float2*)out)[row] = make_float2(1.f / (1.f + expf(-zA[tid])),
                                          1.f / (1.f + expf(-zB[tid])));
        out[2 * BATCH + row] = ldt[tid];
    }
}

extern "C" void kernel_launch(void* const* d_in, const int* in_sizes, int n_in,
                              void* d_out, int out_size, void* d_ws, size_t ws_size,
                              hipStream_t stream) {
    if (ws_size < WS_NEEDED) return;
    PtrPack P;
    for (int k = 0; k < 21; ++k) P.p[k] = (const float*)d_in[k];
    unsigned char* ws = (unsigned char*)d_ws;
    prep_w<<<dim3(1152), dim3(256), 0, stream>>>(P, ws);
    prep_small<<<dim3(73), dim3(256), 0, stream>>>(P, ws);
    realnvp_main<<<dim3(1024), dim3(256), 0, stream>>>((const float*)d_in[0], ws, (float*)d_out);
}